// Round 7
// baseline (925.069 us; speedup 1.0000x reference)
//
#include <hip/hip_runtime.h>
#include <hip/hip_bf16.h>
#include <math.h>

#define N_NODES 50000
#define N_EDGES 800000
#define N_GRAPHS 64
#define HCD 256      // HID*HEADS
#define HIDD 64

// ---------------- CSR build ----------------

__global__ void zero_i32(int* __restrict__ p, int n) {
  int i = blockIdx.x * blockDim.x + threadIdx.x;
  if (i < n) p[i] = 0;
}

__global__ void hist_kernel(const int* __restrict__ dst, int* __restrict__ counts, int ne) {
  int i = blockIdx.x * blockDim.x + threadIdx.x;
  if (i < ne) atomicAdd(&counts[dst[i]], 1);
}

// block-level exclusive scan (256 elems per block), block totals to bsum
__global__ __launch_bounds__(256) void scan1_kernel(const int* __restrict__ counts,
                                                    int* __restrict__ offs,
                                                    int* __restrict__ bsum, int n) {
  int t = threadIdx.x, lane = t & 63, w = t >> 6;
  int i = blockIdx.x * 256 + t;
  int v = (i < n) ? counts[i] : 0;
  int x = v;
  #pragma unroll
  for (int off = 1; off < 64; off <<= 1) {
    int tmp = __shfl_up(x, off);
    if (lane >= off) x += tmp;
  }
  __shared__ int wsum[4], woff[4];
  if (lane == 63) wsum[w] = x;
  __syncthreads();
  if (t == 0) {
    int s = 0;
    #pragma unroll
    for (int k = 0; k < 4; ++k) { woff[k] = s; s += wsum[k]; }
    bsum[blockIdx.x] = s;
  }
  __syncthreads();
  if (i < n) offs[i] = woff[w] + x - v;
}

// exclusive scan of block sums (nblk <= 256) in place
__global__ __launch_bounds__(256) void scan2_kernel(int* __restrict__ bsum, int nblk) {
  int t = threadIdx.x, lane = t & 63, w = t >> 6;
  int v = (t < nblk) ? bsum[t] : 0;
  int x = v;
  #pragma unroll
  for (int off = 1; off < 64; off <<= 1) {
    int tmp = __shfl_up(x, off);
    if (lane >= off) x += tmp;
  }
  __shared__ int wsum[4], woff[4];
  if (lane == 63) wsum[w] = x;
  __syncthreads();
  if (t == 0) {
    int s = 0;
    #pragma unroll
    for (int k = 0; k < 4; ++k) { woff[k] = s; s += wsum[k]; }
  }
  __syncthreads();
  if (t < nblk) bsum[t] = woff[w] + x - v;
}

// add block bases; writes offs[n]=E and cursor copy (fused)
__global__ void scan3_kernel(int* __restrict__ offs, const int* __restrict__ bsum,
                             int* __restrict__ cursor, int n) {
  int i = blockIdx.x * blockDim.x + threadIdx.x;
  if (i < n) {
    int v = offs[i] + bsum[i >> 8];
    offs[i] = v;
    cursor[i] = v;
  } else if (i == n) {
    offs[n] = N_EDGES;
  }
}

__global__ void scatter_kernel(const int* __restrict__ src, const int* __restrict__ dst,
                               const float* __restrict__ ea, int* __restrict__ cursor,
                               int* __restrict__ ssrc, float* __restrict__ sea, int ne) {
  int i = blockIdx.x * blockDim.x + threadIdx.x;
  if (i < ne) {
    int d = dst[i];
    int pos = atomicAdd(&cursor[d], 1);
    ssrc[pos] = src[i];
    sea[pos] = ea[i];
  }
}

// ---------------- encoder ----------------

__global__ void encoder_kernel(const float* __restrict__ x, const float* __restrict__ w,
                               const float* __restrict__ b, float* __restrict__ h0, int n_nodes) {
  int idx = blockIdx.x * blockDim.x + threadIdx.x;
  if (idx >= n_nodes * HIDD) return;
  int n = idx >> 6, c = idx & 63;
  float acc = b[c];
  #pragma unroll
  for (int k = 0; k < 8; ++k) acc += x[n * 8 + k] * w[k * 64 + c];
  h0[idx] = fmaxf(acc, 0.f);
}

// ---------------- node transform: out = h@w + b (one matrix per block) ----------------
// grid = (782, 2): blockIdx.y==0 -> wl/xl, ==1 -> wr/xr. Tile = 64 nodes (NT).
// block = 256 threads = 64 channel-lanes (cx, 4ch each) x 4 node-groups (g, 16 nodes).
// h staged TRANSPOSED in LDS k-tiles hs[kk][node] (16 KB): per k a group reads its 16
// h-values as 4 b128 broadcasts. Weight row (1024 B/wave-k) prefetched 1-deep from L2.
// NPW=16 halves L2 weight traffic vs NPW=8 (1.64 GB -> under the 83us FMA floor).

template<int K>
__global__ __launch_bounds__(256, 4) void transform_kernel(
    const float* __restrict__ h,
    const float* __restrict__ wl, const float* __restrict__ bl,
    const float* __restrict__ wr, const float* __restrict__ br,
    float* __restrict__ xl, float* __restrict__ xr, int n_nodes)
{
  constexpr int NT = 64;
  constexpr int KT = 64;
  __shared__ float hs[KT][NT];          // transposed k-tile, 16 KB
  const int n0 = blockIdx.x * NT;
  const float* __restrict__ w   = blockIdx.y ? wr : wl;
  const float* __restrict__ bb  = blockIdx.y ? br : bl;
  float* __restrict__ outp      = blockIdx.y ? xr : xl;

  const int t  = threadIdx.x;
  const int cx = t & 63;                // channel group: channels 4cx..4cx+3
  const int g  = t >> 6;                // node group: nodes g*16..g*16+15

  float acc[16][4];
  #pragma unroll
  for (int i = 0; i < 16; ++i)
    #pragma unroll
    for (int j = 0; j < 4; ++j) acc[i][j] = 0.f;

  float4 wc = *(const float4*)&w[4 * cx];     // k=0 weight row
  const int sn = t & 63;                      // staging: node within tile

  for (int kt = 0; kt < K; kt += KT) {
    // ---- stage transposed: hs[kk][n] = h[n0+n][kt+kk] ----
    #pragma unroll
    for (int rep = 0; rep < 4; ++rep) {
      int kq = (t >> 6) + rep * 4;            // 0..15 -> 4-col chunk
      float4 v = make_float4(0.f, 0.f, 0.f, 0.f);
      if (n0 + sn < n_nodes) v = *(const float4*)&h[(n0 + sn) * K + kt + 4 * kq];
      hs[4 * kq + 0][sn] = v.x;
      hs[4 * kq + 1][sn] = v.y;
      hs[4 * kq + 2][sn] = v.z;
      hs[4 * kq + 3][sn] = v.w;
    }
    __syncthreads();

    // ---- compute over this k-tile ----
    for (int kk = 0; kk < KT; ++kk) {
      int k = kt + kk;
      float4 wn = wc;
      if (k + 1 < K) wn = *(const float4*)&w[(k + 1) * 256 + 4 * cx];  // prefetch next row
      const float* hrow = &hs[kk][g * 16];
      float4 hA = *(const float4*)&hrow[0];
      float4 hB = *(const float4*)&hrow[4];
      float4 hC = *(const float4*)&hrow[8];
      float4 hD = *(const float4*)&hrow[12];
      #pragma unroll
      for (int j = 0; j < 4; ++j) {
        float hv0 = (j == 0) ? hA.x : (j == 1) ? hA.y : (j == 2) ? hA.z : hA.w;
        float hv1 = (j == 0) ? hB.x : (j == 1) ? hB.y : (j == 2) ? hB.z : hB.w;
        float hv2 = (j == 0) ? hC.x : (j == 1) ? hC.y : (j == 2) ? hC.z : hC.w;
        float hv3 = (j == 0) ? hD.x : (j == 1) ? hD.y : (j == 2) ? hD.z : hD.w;
        acc[j][0]      = fmaf(hv0, wc.x, acc[j][0]);
        acc[j][1]      = fmaf(hv0, wc.y, acc[j][1]);
        acc[j][2]      = fmaf(hv0, wc.z, acc[j][2]);
        acc[j][3]      = fmaf(hv0, wc.w, acc[j][3]);
        acc[j + 4][0]  = fmaf(hv1, wc.x, acc[j + 4][0]);
        acc[j + 4][1]  = fmaf(hv1, wc.y, acc[j + 4][1]);
        acc[j + 4][2]  = fmaf(hv1, wc.z, acc[j + 4][2]);
        acc[j + 4][3]  = fmaf(hv1, wc.w, acc[j + 4][3]);
        acc[j + 8][0]  = fmaf(hv2, wc.x, acc[j + 8][0]);
        acc[j + 8][1]  = fmaf(hv2, wc.y, acc[j + 8][1]);
        acc[j + 8][2]  = fmaf(hv2, wc.z, acc[j + 8][2]);
        acc[j + 8][3]  = fmaf(hv2, wc.w, acc[j + 8][3]);
        acc[j + 12][0] = fmaf(hv3, wc.x, acc[j + 12][0]);
        acc[j + 12][1] = fmaf(hv3, wc.y, acc[j + 12][1]);
        acc[j + 12][2] = fmaf(hv3, wc.z, acc[j + 12][2]);
        acc[j + 12][3] = fmaf(hv3, wc.w, acc[j + 12][3]);
      }
      wc = wn;
    }
    __syncthreads();
  }

  float4 b4 = *(const float4*)&bb[4 * cx];
  #pragma unroll
  for (int i = 0; i < 16; ++i) {
    int n = n0 + g * 16 + i;
    if (n < n_nodes) {
      float4 o;
      o.x = acc[i][0] + b4.x; o.y = acc[i][1] + b4.y;
      o.z = acc[i][2] + b4.z; o.w = acc[i][3] + b4.w;
      *(float4*)&outp[n * 256 + 4 * cx] = o;
    }
  }
}

// ---------------- fused edge logits + online softmax + aggregation ----------------
// one block per dst node; 4 waves stride the node's edge list (1 wave = 1 edge).
// lane l owns channels 4l..4l+3 (all 4 heads per wave); logit reduce = 3 in-lane
// adds + 4-stage 16-lane butterfly. Indices AND the xl gather are pipelined one
// iteration ahead. Flash-style cross-wave merge in LDS.

__global__ __launch_bounds__(256) void gat_aggregate_kernel(
    const float* __restrict__ xl, const float* __restrict__ xr,
    const int* __restrict__ offs, const int* __restrict__ ssrc,
    const float* __restrict__ sea,
    const float* __restrict__ we, const float* __restrict__ att,
    const float* __restrict__ bias, float* __restrict__ out, int n_nodes)
{
  int n = blockIdx.x;
  if (n >= n_nodes) return;
  int t = threadIdx.x, lane = t & 63, wv = t >> 6;
  const float4 xr4 = *(const float4*)&xr[n * HCD + 4 * lane];
  const float4 we4 = *(const float4*)&we[4 * lane];
  const float4 at4 = *(const float4*)&att[4 * lane];
  int beg = offs[n], end = offs[n + 1];
  float runmax = -INFINITY, den = 0.f;
  float4 acc = make_float4(0.f, 0.f, 0.f, 0.f);

  int j = beg + wv;
  float eav = 0.f;
  float4 xlv = make_float4(0.f, 0.f, 0.f, 0.f);
  if (j < end) {
    int s = ssrc[j];
    eav = sea[j];
    xlv = *(const float4*)&xl[s * HCD + 4 * lane];
  }
  while (j < end) {
    int jn = j + 4;
    float ea2 = 0.f;
    float4 xlv2 = make_float4(0.f, 0.f, 0.f, 0.f);
    if (jn < end) {
      int s2 = ssrc[jn];
      ea2 = sea[jn];
      xlv2 = *(const float4*)&xl[s2 * HCD + 4 * lane];   // gather issued early
    }
    float4 m;
    m.x = xlv.x + fmaf(eav, we4.x, xr4.x);
    m.y = xlv.y + fmaf(eav, we4.y, xr4.y);
    m.z = xlv.z + fmaf(eav, we4.z, xr4.z);
    m.w = xlv.w + fmaf(eav, we4.w, xr4.w);
    m.x = (m.x > 0.f) ? m.x : 0.2f * m.x;
    m.y = (m.y > 0.f) ? m.y : 0.2f * m.y;
    m.z = (m.z > 0.f) ? m.z : 0.2f * m.z;
    m.w = (m.w > 0.f) ? m.w : 0.2f * m.w;
    float p = fmaf(m.w, at4.w, fmaf(m.z, at4.z, fmaf(m.y, at4.y, m.x * at4.x)));
    #pragma unroll
    for (int off = 1; off < 16; off <<= 1) p += __shfl_xor(p, off);
    float nm = fmaxf(runmax, p);
    float sc = __expf(runmax - nm);   // first iter: exp(-inf)=0
    float wgt = __expf(p - nm);
    den = fmaf(den, sc, wgt);
    acc.x = fmaf(acc.x, sc, wgt * xlv.x);
    acc.y = fmaf(acc.y, sc, wgt * xlv.y);
    acc.z = fmaf(acc.z, sc, wgt * xlv.z);
    acc.w = fmaf(acc.w, sc, wgt * xlv.w);
    runmax = nm;
    xlv = xlv2; eav = ea2; j = jn;
  }

  __shared__ float smax[4][64], sden[4][64];
  __shared__ float4 sacc[4][64];
  smax[wv][lane] = runmax; sden[wv][lane] = den; sacc[wv][lane] = acc;
  __syncthreads();
  if (wv == 0) {
    float m0 = smax[0][lane], m1 = smax[1][lane], m2 = smax[2][lane], m3 = smax[3][lane];
    float M = fmaxf(fmaxf(m0, m1), fmaxf(m2, m3));
    float4 a = make_float4(0.f, 0.f, 0.f, 0.f);
    if (M > -INFINITY) {
      float s0 = __expf(m0 - M), s1 = __expf(m1 - M), s2 = __expf(m2 - M), s3 = __expf(m3 - M);
      float d = sden[0][lane] * s0 + sden[1][lane] * s1 + sden[2][lane] * s2 + sden[3][lane] * s3;
      float4 a0 = sacc[0][lane], a1 = sacc[1][lane], a2 = sacc[2][lane], a3 = sacc[3][lane];
      a.x = a0.x * s0 + a1.x * s1 + a2.x * s2 + a3.x * s3;
      a.y = a0.y * s0 + a1.y * s1 + a2.y * s2 + a3.y * s3;
      a.z = a0.z * s0 + a1.z * s1 + a2.z * s2 + a3.z * s3;
      a.w = a0.w * s0 + a1.w * s1 + a2.w * s2 + a3.w * s3;
      float inv = 1.f / d;
      a.x *= inv; a.y *= inv; a.z *= inv; a.w *= inv;
    }
    float4 b4 = *(const float4*)&bias[4 * lane];
    float4 o;
    o.x = fmaxf(a.x + b4.x, 0.f);
    o.y = fmaxf(a.y + b4.y, 0.f);
    o.z = fmaxf(a.z + b4.z, 0.f);
    o.w = fmaxf(a.w + b4.w, 0.f);
    *(float4*)&out[n * HCD + 4 * lane] = o;
  }
}

// ---------------- global mean pool (batch is sorted) ----------------

__device__ __forceinline__ int lbound(const int* __restrict__ a, int n, int key) {
  int lo = 0, hi = n;
  while (lo < hi) { int mid = (lo + hi) >> 1; if (a[mid] < key) lo = mid + 1; else hi = mid; }
  return lo;
}

__global__ __launch_bounds__(256) void pool_kernel(const float* __restrict__ h,
                                                   const int* __restrict__ batch,
                                                   float* __restrict__ gmean) {
  int g = blockIdx.x;
  int t = threadIdx.x, lane = t & 63, wv = t >> 6;
  __shared__ int sb, se;
  if (t == 0) {
    sb = lbound(batch, N_NODES, g);
    se = lbound(batch, N_NODES, g + 1);
  }
  __syncthreads();
  int beg = sb, end = se;
  float4 acc = make_float4(0.f, 0.f, 0.f, 0.f);
  for (int n = beg + wv; n < end; n += 4) {
    float4 v = *(const float4*)&h[n * HCD + 4 * lane];
    acc.x += v.x; acc.y += v.y; acc.z += v.z; acc.w += v.w;
  }
  __shared__ float4 sacc[4][64];
  sacc[wv][lane] = acc;
  __syncthreads();
  if (wv == 0) {
    float4 a0 = sacc[0][lane], a1 = sacc[1][lane], a2 = sacc[2][lane], a3 = sacc[3][lane];
    float cnt = (float)((end - beg) > 1 ? (end - beg) : 1);
    float inv = 1.f / cnt;
    float4 o;
    o.x = (a0.x + a1.x + a2.x + a3.x) * inv;
    o.y = (a0.y + a1.y + a2.y + a3.y) * inv;
    o.z = (a0.z + a1.z + a2.z + a3.z) * inv;
    o.w = (a0.w + a1.w + a2.w + a3.w) * inv;
    *(float4*)&gmean[g * HCD + 4 * lane] = o;
  }
}

// ---------------- post MLP: Linear->LN->ReLU->Linear->ReLU->head ----------------

__global__ __launch_bounds__(128) void mlp_kernel(
    const float* __restrict__ gmean,
    const float* __restrict__ p1_w, const float* __restrict__ p1_b,
    const float* __restrict__ ln_g, const float* __restrict__ ln_b,
    const float* __restrict__ p2_w, const float* __restrict__ p2_b,
    const float* __restrict__ head_w, const float* __restrict__ head_b,
    float* __restrict__ out)
{
  int g = blockIdx.x, t = threadIdx.x;
  __shared__ float gv[256];
  __shared__ float zs[128];
  __shared__ float z2s[64];
  __shared__ float sums[2][2];
  gv[t] = gmean[g * 256 + t];
  gv[t + 128] = gmean[g * 256 + 128 + t];
  __syncthreads();
  float acc = p1_b[t];
  for (int k = 0; k < 256; ++k) acc += gv[k] * p1_w[k * 128 + t];
  float s1 = acc, s2 = acc * acc;
  #pragma unroll
  for (int off = 32; off >= 1; off >>= 1) {
    s1 += __shfl_xor(s1, off);
    s2 += __shfl_xor(s2, off);
  }
  int wid = t >> 6, lane = t & 63;
  if (lane == 0) { sums[wid][0] = s1; sums[wid][1] = s2; }
  __syncthreads();
  float S1 = sums[0][0] + sums[1][0];
  float S2 = sums[0][1] + sums[1][1];
  float mu = S1 * (1.f / 128.f);
  float var = S2 * (1.f / 128.f) - mu * mu;
  float rstd = rsqrtf(var + 1e-5f);
  float z = (acc - mu) * rstd * ln_g[t] + ln_b[t];
  zs[t] = fmaxf(z, 0.f);
  __syncthreads();
  if (t < 64) {
    float a2 = p2_b[t];
    for (int k = 0; k < 128; ++k) a2 += zs[k] * p2_w[k * 64 + t];
    z2s[t] = fmaxf(a2, 0.f);
  }
  __syncthreads();
  if (t < 64) {
    float p = z2s[t] * head_w[t];
    #pragma unroll
    for (int off = 32; off >= 1; off >>= 1) p += __shfl_xor(p, off);
    if (t == 0) out[g] = p + head_b[0];
  }
}

// ---------------- launch ----------------

extern "C" void kernel_launch(void* const* d_in, const int* in_sizes, int n_in,
                              void* d_out, int out_size, void* d_ws, size_t ws_size,
                              hipStream_t stream) {
  const float* x       = (const float*)d_in[0];
  const float* ea      = (const float*)d_in[1];
  const int*   eidx    = (const int*)d_in[2];
  const int*   batch   = (const int*)d_in[3];
  const float* enc_w   = (const float*)d_in[4];
  const float* enc_b   = (const float*)d_in[5];
  const float* g1_wl   = (const float*)d_in[6];
  const float* g1_bl   = (const float*)d_in[7];
  const float* g1_wr   = (const float*)d_in[8];
  const float* g1_br   = (const float*)d_in[9];
  const float* g1_we   = (const float*)d_in[10];
  const float* g1_att  = (const float*)d_in[11];
  const float* g1_bias = (const float*)d_in[12];
  const float* g2_wl   = (const float*)d_in[13];
  const float* g2_bl   = (const float*)d_in[14];
  const float* g2_wr   = (const float*)d_in[15];
  const float* g2_br   = (const float*)d_in[16];
  const float* g2_we   = (const float*)d_in[17];
  const float* g2_att  = (const float*)d_in[18];
  const float* g2_bias = (const float*)d_in[19];
  const float* p1_w    = (const float*)d_in[20];
  const float* p1_b    = (const float*)d_in[21];
  const float* ln_g    = (const float*)d_in[22];
  const float* ln_b    = (const float*)d_in[23];
  const float* p2_w    = (const float*)d_in[24];
  const float* p2_b    = (const float*)d_in[25];
  const float* head_w  = (const float*)d_in[26];
  const float* head_b  = (const float*)d_in[27];

  const int* src = eidx;
  const int* dst = eidx + N_EDGES;

  char* wsp = (char*)d_ws;
  size_t off = 0;
  auto alloc = [&](size_t bytes) -> void* {
    void* p = wsp + off;
    off += (bytes + 255) & ~(size_t)255;
    return p;
  };
  float* h0     = (float*)alloc((size_t)N_NODES * 64 * 4);
  float* hA     = (float*)alloc((size_t)N_NODES * 256 * 4);
  float* xl     = (float*)alloc((size_t)N_NODES * 256 * 4);
  float* xr     = (float*)alloc((size_t)N_NODES * 256 * 4);
  int*   counts = (int*)alloc((size_t)N_NODES * 4);
  int*   offs   = (int*)alloc((size_t)(N_NODES + 1) * 4);
  int*   cursor = (int*)alloc((size_t)N_NODES * 4);
  int*   bsum   = (int*)alloc((size_t)256 * 4);
  int*   ssrc   = (int*)alloc((size_t)N_EDGES * 4);
  float* seaf   = (float*)alloc((size_t)N_EDGES * 4);
  float* gmean  = (float*)alloc((size_t)N_GRAPHS * 256 * 4);

  const int NBLK = (N_NODES + 255) / 256;  // 196

  // --- CSR by dst (built once, reused by both GAT layers) ---
  zero_i32<<<NBLK, 256, 0, stream>>>(counts, N_NODES);
  hist_kernel<<<(N_EDGES + 255) / 256, 256, 0, stream>>>(dst, counts, N_EDGES);
  scan1_kernel<<<NBLK, 256, 0, stream>>>(counts, offs, bsum, N_NODES);
  scan2_kernel<<<1, 256, 0, stream>>>(bsum, NBLK);
  scan3_kernel<<<(N_NODES + 256) / 256, 256, 0, stream>>>(offs, bsum, cursor, N_NODES);
  scatter_kernel<<<(N_EDGES + 255) / 256, 256, 0, stream>>>(src, dst, ea, cursor, ssrc, seaf, N_EDGES);

  // --- encoder ---
  encoder_kernel<<<(N_NODES * 64 + 255) / 256, 256, 0, stream>>>(x, enc_w, enc_b, h0, N_NODES);

  const dim3 tgrid((N_NODES + 63) / 64, 2);   // 782 x 2

  // --- GAT layer 1 (in = 64) ---
  transform_kernel<64><<<tgrid, 256, 0, stream>>>(
      h0, g1_wl, g1_bl, g1_wr, g1_br, xl, xr, N_NODES);
  gat_aggregate_kernel<<<N_NODES, 256, 0, stream>>>(
      xl, xr, offs, ssrc, seaf, g1_we, g1_att, g1_bias, hA, N_NODES);

  // --- GAT layer 2 (in = 256) ---
  transform_kernel<256><<<tgrid, 256, 0, stream>>>(
      hA, g2_wl, g2_bl, g2_wr, g2_br, xl, xr, N_NODES);
  gat_aggregate_kernel<<<N_NODES, 256, 0, stream>>>(
      xl, xr, offs, ssrc, seaf, g2_we, g2_att, g2_bias, hA, N_NODES);

  // --- pool + MLP head ---
  pool_kernel<<<N_GRAPHS, 256, 0, stream>>>(hA, batch, gmean);
  mlp_kernel<<<N_GRAPHS, 128, 0, stream>>>(gmean, p1_w, p1_b, ln_g, ln_b,
                                           p2_w, p2_b, head_w, head_b, (float*)d_out);
}

// Round 11
// 766.939 us; speedup vs baseline: 1.2062x; 1.2062x over previous
//
#include <hip/hip_runtime.h>
#include <hip/hip_bf16.h>
#include <math.h>

#define N_NODES 50000
#define N_EDGES 800000
#define N_GRAPHS 64
#define HCD 256      // HID*HEADS
#define HIDD 64

// ---------------- CSR build ----------------

__global__ void zero_i32(int* __restrict__ p, int n) {
  int i = blockIdx.x * blockDim.x + threadIdx.x;
  if (i < n) p[i] = 0;
}

__global__ void hist_kernel(const int* __restrict__ dst, int* __restrict__ counts, int ne) {
  int i = blockIdx.x * blockDim.x + threadIdx.x;
  if (i < ne) atomicAdd(&counts[dst[i]], 1);
}

// block-level exclusive scan (256 elems per block), block totals to bsum
__global__ __launch_bounds__(256) void scan1_kernel(const int* __restrict__ counts,
                                                    int* __restrict__ offs,
                                                    int* __restrict__ bsum, int n) {
  int t = threadIdx.x, lane = t & 63, w = t >> 6;
  int i = blockIdx.x * 256 + t;
  int v = (i < n) ? counts[i] : 0;
  int x = v;
  #pragma unroll
  for (int off = 1; off < 64; off <<= 1) {
    int tmp = __shfl_up(x, off);
    if (lane >= off) x += tmp;
  }
  __shared__ int wsum[4], woff[4];
  if (lane == 63) wsum[w] = x;
  __syncthreads();
  if (t == 0) {
    int s = 0;
    #pragma unroll
    for (int k = 0; k < 4; ++k) { woff[k] = s; s += wsum[k]; }
    bsum[blockIdx.x] = s;
  }
  __syncthreads();
  if (i < n) offs[i] = woff[w] + x - v;
}

// exclusive scan of block sums (nblk <= 256) in place
__global__ __launch_bounds__(256) void scan2_kernel(int* __restrict__ bsum, int nblk) {
  int t = threadIdx.x, lane = t & 63, w = t >> 6;
  int v = (t < nblk) ? bsum[t] : 0;
  int x = v;
  #pragma unroll
  for (int off = 1; off < 64; off <<= 1) {
    int tmp = __shfl_up(x, off);
    if (lane >= off) x += tmp;
  }
  __shared__ int wsum[4], woff[4];
  if (lane == 63) wsum[w] = x;
  __syncthreads();
  if (t == 0) {
    int s = 0;
    #pragma unroll
    for (int k = 0; k < 4; ++k) { woff[k] = s; s += wsum[k]; }
  }
  __syncthreads();
  if (t < nblk) bsum[t] = woff[w] + x - v;
}

// add block bases; writes offs[n]=E and cursor copy (fused)
__global__ void scan3_kernel(int* __restrict__ offs, const int* __restrict__ bsum,
                             int* __restrict__ cursor, int n) {
  int i = blockIdx.x * blockDim.x + threadIdx.x;
  if (i < n) {
    int v = offs[i] + bsum[i >> 8];
    offs[i] = v;
    cursor[i] = v;
  } else if (i == n) {
    offs[n] = N_EDGES;
  }
}

__global__ void scatter_kernel(const int* __restrict__ src, const int* __restrict__ dst,
                               const float* __restrict__ ea, int* __restrict__ cursor,
                               int* __restrict__ ssrc, float* __restrict__ sea, int ne) {
  int i = blockIdx.x * blockDim.x + threadIdx.x;
  if (i < ne) {
    int d = dst[i];
    int pos = atomicAdd(&cursor[d], 1);
    ssrc[pos] = src[i];
    sea[pos] = ea[i];
  }
}

// ---------------- encoder ----------------

__global__ void encoder_kernel(const float* __restrict__ x, const float* __restrict__ w,
                               const float* __restrict__ b, float* __restrict__ h0, int n_nodes) {
  int idx = blockIdx.x * blockDim.x + threadIdx.x;
  if (idx >= n_nodes * HIDD) return;
  int n = idx >> 6, c = idx & 63;
  float acc = b[c];
  #pragma unroll
  for (int k = 0; k < 8; ++k) acc += x[n * 8 + k] * w[k * 64 + c];
  h0[idx] = fmaxf(acc, 0.f);
}

// ---------------- node transform: out = h@w + b (one matrix per block) ----------------
// R6-proven structure (183us, VGPR 44, no spills). grid = (tiles, 2):
// blockIdx.y==0 -> wl/xl, ==1 -> wr/xr. block = 256: 64 ch-lanes x 4 node-groups (8 nodes).
// Per k: 8 LDS scalar broadcasts + 32 FMA; next weight row prefetched 1-deep.

template<int K>
__global__ __launch_bounds__(256) void transform_kernel(
    const float* __restrict__ h,
    const float* __restrict__ wl, const float* __restrict__ bl,
    const float* __restrict__ wr, const float* __restrict__ br,
    float* __restrict__ xl, float* __restrict__ xr, int n_nodes)
{
  constexpr int NT = 32;
  __shared__ float hs[NT * K];
  int n0 = blockIdx.x * NT;
  const float* __restrict__ w   = blockIdx.y ? wr : wl;
  const float* __restrict__ bb  = blockIdx.y ? br : bl;
  float* __restrict__ outp      = blockIdx.y ? xr : xl;

  for (int idx4 = threadIdx.x; idx4 < NT * K / 4; idx4 += 256) {
    int i = idx4 / (K / 4), kq = idx4 - i * (K / 4);
    int n = n0 + i;
    float4 v = make_float4(0.f, 0.f, 0.f, 0.f);
    if (n < n_nodes) v = *(const float4*)&h[n * K + 4 * kq];
    *(float4*)&hs[i * K + 4 * kq] = v;
  }
  __syncthreads();

  const int cx = threadIdx.x & 63;
  const int ny = threadIdx.x >> 6;
  float acc[8][4];
  #pragma unroll
  for (int i = 0; i < 8; ++i)
    #pragma unroll
    for (int j = 0; j < 4; ++j) acc[i][j] = 0.f;

  const float* hrow = &hs[(ny * 8) * K];
  float4 wc = *(const float4*)&w[4 * cx];          // k=0 row
  for (int k = 0; k < K; ++k) {
    float4 wn = wc;
    if (k + 1 < K) wn = *(const float4*)&w[(k + 1) * 256 + 4 * cx];  // prefetch
    #pragma unroll
    for (int i = 0; i < 8; ++i) {
      float hv = hrow[i * K + k];                  // LDS broadcast (wave-uniform addr)
      acc[i][0] = fmaf(hv, wc.x, acc[i][0]);
      acc[i][1] = fmaf(hv, wc.y, acc[i][1]);
      acc[i][2] = fmaf(hv, wc.z, acc[i][2]);
      acc[i][3] = fmaf(hv, wc.w, acc[i][3]);
    }
    wc = wn;
  }

  float4 b4 = *(const float4*)&bb[4 * cx];
  #pragma unroll
  for (int i = 0; i < 8; ++i) {
    int n = n0 + ny * 8 + i;
    if (n < n_nodes) {
      float4 o;
      o.x = acc[i][0] + b4.x; o.y = acc[i][1] + b4.y;
      o.z = acc[i][2] + b4.z; o.w = acc[i][3] + b4.w;
      *(float4*)&outp[n * 256 + 4 * cx] = o;
    }
  }
}

// ---------------- fused edge logits + online softmax + aggregation ----------------
// ONE WAVE PER DST NODE (4 nodes per 256-thread block). No LDS, no merge, no
// syncthreads. lane l owns channels 4l..4l+3 (all 4 heads); logit reduce = 3 in-lane
// FMAs + 4-stage 16-lane butterfly. Gather pipelined 1 edge ahead.

__global__ __launch_bounds__(256) void gat_aggregate_kernel(
    const float* __restrict__ xl, const float* __restrict__ xr,
    const int* __restrict__ offs, const int* __restrict__ ssrc,
    const float* __restrict__ sea,
    const float* __restrict__ we, const float* __restrict__ att,
    const float* __restrict__ bias, float* __restrict__ out, int n_nodes)
{
  int n = blockIdx.x * 4 + (threadIdx.x >> 6);   // node handled by this wave
  if (n >= n_nodes) return;                      // wave-uniform exit
  int lane = threadIdx.x & 63;
  const float4 xr4 = *(const float4*)&xr[n * HCD + 4 * lane];
  const float4 we4 = *(const float4*)&we[4 * lane];
  const float4 at4 = *(const float4*)&att[4 * lane];
  int beg = offs[n], end = offs[n + 1];
  float runmax = -INFINITY, den = 0.f;
  float4 acc = make_float4(0.f, 0.f, 0.f, 0.f);

  int j = beg;
  float eav = 0.f;
  float4 xlv = make_float4(0.f, 0.f, 0.f, 0.f);
  if (j < end) {
    int s = ssrc[j];
    eav = sea[j];
    xlv = *(const float4*)&xl[s * HCD + 4 * lane];
  }
  while (j < end) {
    int jn = j + 1;
    float ea2 = 0.f;
    float4 xlv2 = make_float4(0.f, 0.f, 0.f, 0.f);
    if (jn < end) {
      int s2 = ssrc[jn];
      ea2 = sea[jn];
      xlv2 = *(const float4*)&xl[s2 * HCD + 4 * lane];   // gather issued early
    }
    float4 m;
    m.x = xlv.x + fmaf(eav, we4.x, xr4.x);
    m.y = xlv.y + fmaf(eav, we4.y, xr4.y);
    m.z = xlv.z + fmaf(eav, we4.z, xr4.z);
    m.w = xlv.w + fmaf(eav, we4.w, xr4.w);
    m.x = (m.x > 0.f) ? m.x : 0.2f * m.x;
    m.y = (m.y > 0.f) ? m.y : 0.2f * m.y;
    m.z = (m.z > 0.f) ? m.z : 0.2f * m.z;
    m.w = (m.w > 0.f) ? m.w : 0.2f * m.w;
    float p = fmaf(m.w, at4.w, fmaf(m.z, at4.z, fmaf(m.y, at4.y, m.x * at4.x)));
    #pragma unroll
    for (int off = 1; off < 16; off <<= 1) p += __shfl_xor(p, off);
    float nm = fmaxf(runmax, p);
    float sc = __expf(runmax - nm);   // first iter: exp(-inf)=0
    float wgt = __expf(p - nm);
    den = fmaf(den, sc, wgt);
    acc.x = fmaf(acc.x, sc, wgt * xlv.x);
    acc.y = fmaf(acc.y, sc, wgt * xlv.y);
    acc.z = fmaf(acc.z, sc, wgt * xlv.z);
    acc.w = fmaf(acc.w, sc, wgt * xlv.w);
    runmax = nm;
    xlv = xlv2; eav = ea2; j = jn;
  }

  float inv = (end > beg) ? (1.f / den) : 0.f;
  float4 b4 = *(const float4*)&bias[4 * lane];
  float4 o;
  o.x = fmaxf(fmaf(acc.x, inv, b4.x), 0.f);
  o.y = fmaxf(fmaf(acc.y, inv, b4.y), 0.f);
  o.z = fmaxf(fmaf(acc.z, inv, b4.z), 0.f);
  o.w = fmaxf(fmaf(acc.w, inv, b4.w), 0.f);
  *(float4*)&out[n * HCD + 4 * lane] = o;
}

// ---------------- global mean pool (batch is sorted) ----------------

__device__ __forceinline__ int lbound(const int* __restrict__ a, int n, int key) {
  int lo = 0, hi = n;
  while (lo < hi) { int mid = (lo + hi) >> 1; if (a[mid] < key) lo = mid + 1; else hi = mid; }
  return lo;
}

__global__ __launch_bounds__(256) void pool_kernel(const float* __restrict__ h,
                                                   const int* __restrict__ batch,
                                                   float* __restrict__ gmean) {
  int g = blockIdx.x;
  int t = threadIdx.x, lane = t & 63, wv = t >> 6;
  __shared__ int sb, se;
  if (t == 0) {
    sb = lbound(batch, N_NODES, g);
    se = lbound(batch, N_NODES, g + 1);
  }
  __syncthreads();
  int beg = sb, end = se;
  float4 acc = make_float4(0.f, 0.f, 0.f, 0.f);
  for (int n = beg + wv; n < end; n += 4) {
    float4 v = *(const float4*)&h[n * HCD + 4 * lane];
    acc.x += v.x; acc.y += v.y; acc.z += v.z; acc.w += v.w;
  }
  __shared__ float4 sacc[4][64];
  sacc[wv][lane] = acc;
  __syncthreads();
  if (wv == 0) {
    float4 a0 = sacc[0][lane], a1 = sacc[1][lane], a2 = sacc[2][lane], a3 = sacc[3][lane];
    float cnt = (float)((end - beg) > 1 ? (end - beg) : 1);
    float inv = 1.f / cnt;
    float4 o;
    o.x = (a0.x + a1.x + a2.x + a3.x) * inv;
    o.y = (a0.y + a1.y + a2.y + a3.y) * inv;
    o.z = (a0.z + a1.z + a2.z + a3.z) * inv;
    o.w = (a0.w + a1.w + a2.w + a3.w) * inv;
    *(float4*)&gmean[g * HCD + 4 * lane] = o;
  }
}

// ---------------- post MLP: Linear->LN->ReLU->Linear->ReLU->head ----------------

__global__ __launch_bounds__(128) void mlp_kernel(
    const float* __restrict__ gmean,
    const float* __restrict__ p1_w, const float* __restrict__ p1_b,
    const float* __restrict__ ln_g, const float* __restrict__ ln_b,
    const float* __restrict__ p2_w, const float* __restrict__ p2_b,
    const float* __restrict__ head_w, const float* __restrict__ head_b,
    float* __restrict__ out)
{
  int g = blockIdx.x, t = threadIdx.x;
  __shared__ float gv[256];
  __shared__ float zs[128];
  __shared__ float z2s[64];
  __shared__ float sums[2][2];
  gv[t] = gmean[g * 256 + t];
  gv[t + 128] = gmean[g * 256 + 128 + t];
  __syncthreads();
  float acc = p1_b[t];
  for (int k = 0; k < 256; ++k) acc += gv[k] * p1_w[k * 128 + t];
  float s1 = acc, s2 = acc * acc;
  #pragma unroll
  for (int off = 32; off >= 1; off >>= 1) {
    s1 += __shfl_xor(s1, off);
    s2 += __shfl_xor(s2, off);
  }
  int wid = t >> 6, lane = t & 63;
  if (lane == 0) { sums[wid][0] = s1; sums[wid][1] = s2; }
  __syncthreads();
  float S1 = sums[0][0] + sums[1][0];
  float S2 = sums[0][1] + sums[1][1];
  float mu = S1 * (1.f / 128.f);
  float var = S2 * (1.f / 128.f) - mu * mu;
  float rstd = rsqrtf(var + 1e-5f);
  float z = (acc - mu) * rstd * ln_g[t] + ln_b[t];
  zs[t] = fmaxf(z, 0.f);
  __syncthreads();
  if (t < 64) {
    float a2 = p2_b[t];
    for (int k = 0; k < 128; ++k) a2 += zs[k] * p2_w[k * 64 + t];
    z2s[t] = fmaxf(a2, 0.f);
  }
  __syncthreads();
  if (t < 64) {
    float p = z2s[t] * head_w[t];
    #pragma unroll
    for (int off = 32; off >= 1; off >>= 1) p += __shfl_xor(p, off);
    if (t == 0) out[g] = p + head_b[0];
  }
}

// ---------------- launch ----------------

extern "C" void kernel_launch(void* const* d_in, const int* in_sizes, int n_in,
                              void* d_out, int out_size, void* d_ws, size_t ws_size,
                              hipStream_t stream) {
  const float* x       = (const float*)d_in[0];
  const float* ea      = (const float*)d_in[1];
  const int*   eidx    = (const int*)d_in[2];
  const int*   batch   = (const int*)d_in[3];
  const float* enc_w   = (const float*)d_in[4];
  const float* enc_b   = (const float*)d_in[5];
  const float* g1_wl   = (const float*)d_in[6];
  const float* g1_bl   = (const float*)d_in[7];
  const float* g1_wr   = (const float*)d_in[8];
  const float* g1_br   = (const float*)d_in[9];
  const float* g1_we   = (const float*)d_in[10];
  const float* g1_att  = (const float*)d_in[11];
  const float* g1_bias = (const float*)d_in[12];
  const float* g2_wl   = (const float*)d_in[13];
  const float* g2_bl   = (const float*)d_in[14];
  const float* g2_wr   = (const float*)d_in[15];
  const float* g2_br   = (const float*)d_in[16];
  const float* g2_we   = (const float*)d_in[17];
  const float* g2_att  = (const float*)d_in[18];
  const float* g2_bias = (const float*)d_in[19];
  const float* p1_w    = (const float*)d_in[20];
  const float* p1_b    = (const float*)d_in[21];
  const float* ln_g    = (const float*)d_in[22];
  const float* ln_b    = (const float*)d_in[23];
  const float* p2_w    = (const float*)d_in[24];
  const float* p2_b    = (const float*)d_in[25];
  const float* head_w  = (const float*)d_in[26];
  const float* head_b  = (const float*)d_in[27];

  const int* src = eidx;
  const int* dst = eidx + N_EDGES;

  char* wsp = (char*)d_ws;
  size_t off = 0;
  auto alloc = [&](size_t bytes) -> void* {
    void* p = wsp + off;
    off += (bytes + 255) & ~(size_t)255;
    return p;
  };
  float* h0     = (float*)alloc((size_t)N_NODES * 64 * 4);
  float* hA     = (float*)alloc((size_t)N_NODES * 256 * 4);
  float* xl     = (float*)alloc((size_t)N_NODES * 256 * 4);
  float* xr     = (float*)alloc((size_t)N_NODES * 256 * 4);
  int*   counts = (int*)alloc((size_t)N_NODES * 4);
  int*   offs   = (int*)alloc((size_t)(N_NODES + 1) * 4);
  int*   cursor = (int*)alloc((size_t)N_NODES * 4);
  int*   bsum   = (int*)alloc((size_t)256 * 4);
  int*   ssrc   = (int*)alloc((size_t)N_EDGES * 4);
  float* seaf   = (float*)alloc((size_t)N_EDGES * 4);
  float* gmean  = (float*)alloc((size_t)N_GRAPHS * 256 * 4);

  const int NBLK = (N_NODES + 255) / 256;  // 196

  // --- CSR by dst (built once, reused by both GAT layers) ---
  zero_i32<<<NBLK, 256, 0, stream>>>(counts, N_NODES);
  hist_kernel<<<(N_EDGES + 255) / 256, 256, 0, stream>>>(dst, counts, N_EDGES);
  scan1_kernel<<<NBLK, 256, 0, stream>>>(counts, offs, bsum, N_NODES);
  scan2_kernel<<<1, 256, 0, stream>>>(bsum, NBLK);
  scan3_kernel<<<(N_NODES + 256) / 256, 256, 0, stream>>>(offs, bsum, cursor, N_NODES);
  scatter_kernel<<<(N_EDGES + 255) / 256, 256, 0, stream>>>(src, dst, ea, cursor, ssrc, seaf, N_EDGES);

  // --- encoder ---
  encoder_kernel<<<(N_NODES * 64 + 255) / 256, 256, 0, stream>>>(x, enc_w, enc_b, h0, N_NODES);

  const dim3 tgrid((N_NODES + 31) / 32, 2);
  const int AGG_BLOCKS = (N_NODES + 3) / 4;   // 12500, 1 wave per node

  // --- GAT layer 1 (in = 64) ---
  transform_kernel<64><<<tgrid, 256, 0, stream>>>(
      h0, g1_wl, g1_bl, g1_wr, g1_br, xl, xr, N_NODES);
  gat_aggregate_kernel<<<AGG_BLOCKS, 256, 0, stream>>>(
      xl, xr, offs, ssrc, seaf, g1_we, g1_att, g1_bias, hA, N_NODES);

  // --- GAT layer 2 (in = 256) ---
  transform_kernel<256><<<tgrid, 256, 0, stream>>>(
      hA, g2_wl, g2_bl, g2_wr, g2_br, xl, xr, N_NODES);
  gat_aggregate_kernel<<<AGG_BLOCKS, 256, 0, stream>>>(
      xl, xr, offs, ssrc, seaf, g2_we, g2_att, g2_bias, hA, N_NODES);

  // --- pool + MLP head ---
  pool_kernel<<<N_GRAPHS, 256, 0, stream>>>(hA, batch, gmean);
  mlp_kernel<<<N_GRAPHS, 128, 0, stream>>>(gmean, p1_w, p1_b, ln_g, ln_b,
                                           p2_w, p2_b, head_w, head_b, (float*)d_out);
}

// Round 12
// 731.409 us; speedup vs baseline: 1.2648x; 1.0486x over previous
//
#include <hip/hip_runtime.h>
#include <hip/hip_bf16.h>
#include <math.h>

#define N_NODES 50000
#define N_EDGES 800000
#define N_GRAPHS 64
#define HCD 256      // HID*HEADS
#define HIDD 64

__device__ __forceinline__ unsigned short f2bf(float f) {
  __hip_bfloat16 b = __float2bfloat16(f);   // round-to-nearest-even
  return *reinterpret_cast<unsigned short*>(&b);
}
__device__ __forceinline__ float bf2f(unsigned short u) {
  unsigned int x = ((unsigned int)u) << 16;
  return __builtin_bit_cast(float, x);
}

// ---------------- CSR build ----------------

__global__ void zero_i32(int* __restrict__ p, int n) {
  int i = blockIdx.x * blockDim.x + threadIdx.x;
  if (i < n) p[i] = 0;
}

__global__ void hist_kernel(const int* __restrict__ dst, int* __restrict__ counts, int ne) {
  int i = blockIdx.x * blockDim.x + threadIdx.x;
  if (i < ne) atomicAdd(&counts[dst[i]], 1);
}

// block-level exclusive scan (256 elems per block), block totals to bsum
__global__ __launch_bounds__(256) void scan1_kernel(const int* __restrict__ counts,
                                                    int* __restrict__ offs,
                                                    int* __restrict__ bsum, int n) {
  int t = threadIdx.x, lane = t & 63, w = t >> 6;
  int i = blockIdx.x * 256 + t;
  int v = (i < n) ? counts[i] : 0;
  int x = v;
  #pragma unroll
  for (int off = 1; off < 64; off <<= 1) {
    int tmp = __shfl_up(x, off);
    if (lane >= off) x += tmp;
  }
  __shared__ int wsum[4], woff[4];
  if (lane == 63) wsum[w] = x;
  __syncthreads();
  if (t == 0) {
    int s = 0;
    #pragma unroll
    for (int k = 0; k < 4; ++k) { woff[k] = s; s += wsum[k]; }
    bsum[blockIdx.x] = s;
  }
  __syncthreads();
  if (i < n) offs[i] = woff[w] + x - v;
}

// exclusive scan of block sums (nblk <= 256) in place
__global__ __launch_bounds__(256) void scan2_kernel(int* __restrict__ bsum, int nblk) {
  int t = threadIdx.x, lane = t & 63, w = t >> 6;
  int v = (t < nblk) ? bsum[t] : 0;
  int x = v;
  #pragma unroll
  for (int off = 1; off < 64; off <<= 1) {
    int tmp = __shfl_up(x, off);
    if (lane >= off) x += tmp;
  }
  __shared__ int wsum[4], woff[4];
  if (lane == 63) wsum[w] = x;
  __syncthreads();
  if (t == 0) {
    int s = 0;
    #pragma unroll
    for (int k = 0; k < 4; ++k) { woff[k] = s; s += wsum[k]; }
  }
  __syncthreads();
  if (t < nblk) bsum[t] = woff[w] + x - v;
}

// add block bases; writes offs[n]=E and cursor copy (fused)
__global__ void scan3_kernel(int* __restrict__ offs, const int* __restrict__ bsum,
                             int* __restrict__ cursor, int n) {
  int i = blockIdx.x * blockDim.x + threadIdx.x;
  if (i < n) {
    int v = offs[i] + bsum[i >> 8];
    offs[i] = v;
    cursor[i] = v;
  } else if (i == n) {
    offs[n] = N_EDGES;
  }
}

__global__ void scatter_kernel(const int* __restrict__ src, const int* __restrict__ dst,
                               const float* __restrict__ ea, int* __restrict__ cursor,
                               int* __restrict__ ssrc, float* __restrict__ sea, int ne) {
  int i = blockIdx.x * blockDim.x + threadIdx.x;
  if (i < ne) {
    int d = dst[i];
    int pos = atomicAdd(&cursor[d], 1);
    ssrc[pos] = src[i];
    sea[pos] = ea[i];
  }
}

// ---------------- encoder ----------------

__global__ void encoder_kernel(const float* __restrict__ x, const float* __restrict__ w,
                               const float* __restrict__ b, float* __restrict__ h0, int n_nodes) {
  int idx = blockIdx.x * blockDim.x + threadIdx.x;
  if (idx >= n_nodes * HIDD) return;
  int n = idx >> 6, c = idx & 63;
  float acc = b[c];
  #pragma unroll
  for (int k = 0; k < 8; ++k) acc += x[n * 8 + k] * w[k * 64 + c];
  h0[idx] = fmaxf(acc, 0.f);
}

// ---------------- node transform: out = h@w + b (one matrix per block) ----------------
// R6-proven structure (183us, VGPR 44, no spills). grid = (tiles, 2):
// blockIdx.y==0 -> wl -> xl stored BF16 (gathered 16x/row by aggregate: bytes halved),
// blockIdx.y==1 -> wr -> xr stored F32 (read once per node, keep full precision).
// block = 256: 64 ch-lanes x 4 node-groups (8 nodes). Per k: 8 LDS scalar broadcasts
// + 32 FMA; next weight row prefetched 1-deep.

template<int K>
__global__ __launch_bounds__(256) void transform_kernel(
    const float* __restrict__ h,
    const float* __restrict__ wl, const float* __restrict__ bl,
    const float* __restrict__ wr, const float* __restrict__ br,
    unsigned short* __restrict__ xlb, float* __restrict__ xr, int n_nodes)
{
  constexpr int NT = 32;
  __shared__ float hs[NT * K];
  int n0 = blockIdx.x * NT;
  const float* __restrict__ w   = blockIdx.y ? wr : wl;
  const float* __restrict__ bb  = blockIdx.y ? br : bl;

  for (int idx4 = threadIdx.x; idx4 < NT * K / 4; idx4 += 256) {
    int i = idx4 / (K / 4), kq = idx4 - i * (K / 4);
    int n = n0 + i;
    float4 v = make_float4(0.f, 0.f, 0.f, 0.f);
    if (n < n_nodes) v = *(const float4*)&h[n * K + 4 * kq];
    *(float4*)&hs[i * K + 4 * kq] = v;
  }
  __syncthreads();

  const int cx = threadIdx.x & 63;
  const int ny = threadIdx.x >> 6;
  float acc[8][4];
  #pragma unroll
  for (int i = 0; i < 8; ++i)
    #pragma unroll
    for (int j = 0; j < 4; ++j) acc[i][j] = 0.f;

  const float* hrow = &hs[(ny * 8) * K];
  float4 wc = *(const float4*)&w[4 * cx];          // k=0 row
  for (int k = 0; k < K; ++k) {
    float4 wn = wc;
    if (k + 1 < K) wn = *(const float4*)&w[(k + 1) * 256 + 4 * cx];  // prefetch
    #pragma unroll
    for (int i = 0; i < 8; ++i) {
      float hv = hrow[i * K + k];                  // LDS broadcast (wave-uniform addr)
      acc[i][0] = fmaf(hv, wc.x, acc[i][0]);
      acc[i][1] = fmaf(hv, wc.y, acc[i][1]);
      acc[i][2] = fmaf(hv, wc.z, acc[i][2]);
      acc[i][3] = fmaf(hv, wc.w, acc[i][3]);
    }
    wc = wn;
  }

  float4 b4 = *(const float4*)&bb[4 * cx];
  if (blockIdx.y == 0) {
    #pragma unroll
    for (int i = 0; i < 8; ++i) {
      int n = n0 + ny * 8 + i;
      if (n < n_nodes) {
        ushort4 o;
        o.x = f2bf(acc[i][0] + b4.x);
        o.y = f2bf(acc[i][1] + b4.y);
        o.z = f2bf(acc[i][2] + b4.z);
        o.w = f2bf(acc[i][3] + b4.w);
        *(ushort4*)&xlb[n * 256 + 4 * cx] = o;
      }
    }
  } else {
    #pragma unroll
    for (int i = 0; i < 8; ++i) {
      int n = n0 + ny * 8 + i;
      if (n < n_nodes) {
        float4 o;
        o.x = acc[i][0] + b4.x; o.y = acc[i][1] + b4.y;
        o.z = acc[i][2] + b4.z; o.w = acc[i][3] + b4.w;
        *(float4*)&xr[n * 256 + 4 * cx] = o;
      }
    }
  }
}

// ---------------- fused edge logits + online softmax + aggregation ----------------
// ONE WAVE PER DST NODE (4 nodes per 256-thread block). xl gathered as BF16
// (512B/edge-row instead of 1KB - the aggregate is gather-BW-bound through L3;
// R6 vs R11 A/B showed sync structure is irrelevant). lane l owns channels
// 4l..4l+3; logit reduce = 3 in-lane FMAs + 4-stage 16-lane butterfly.
// Gather pipelined 1 edge ahead.

__global__ __launch_bounds__(256) void gat_aggregate_kernel(
    const unsigned short* __restrict__ xlb, const float* __restrict__ xr,
    const int* __restrict__ offs, const int* __restrict__ ssrc,
    const float* __restrict__ sea,
    const float* __restrict__ we, const float* __restrict__ att,
    const float* __restrict__ bias, float* __restrict__ out, int n_nodes)
{
  int n = blockIdx.x * 4 + (threadIdx.x >> 6);   // node handled by this wave
  if (n >= n_nodes) return;                      // wave-uniform exit
  int lane = threadIdx.x & 63;
  const float4 xr4 = *(const float4*)&xr[n * HCD + 4 * lane];
  const float4 we4 = *(const float4*)&we[4 * lane];
  const float4 at4 = *(const float4*)&att[4 * lane];
  int beg = offs[n], end = offs[n + 1];
  float runmax = -INFINITY, den = 0.f;
  float4 acc = make_float4(0.f, 0.f, 0.f, 0.f);

  int j = beg;
  float eav = 0.f;
  ushort4 xu = make_ushort4(0, 0, 0, 0);
  if (j < end) {
    int s = ssrc[j];
    eav = sea[j];
    xu = *(const ushort4*)&xlb[s * HCD + 4 * lane];
  }
  while (j < end) {
    int jn = j + 1;
    float ea2 = 0.f;
    ushort4 xu2 = make_ushort4(0, 0, 0, 0);
    if (jn < end) {
      int s2 = ssrc[jn];
      ea2 = sea[jn];
      xu2 = *(const ushort4*)&xlb[s2 * HCD + 4 * lane];   // gather issued early
    }
    float4 xlv = make_float4(bf2f(xu.x), bf2f(xu.y), bf2f(xu.z), bf2f(xu.w));
    float4 m;
    m.x = xlv.x + fmaf(eav, we4.x, xr4.x);
    m.y = xlv.y + fmaf(eav, we4.y, xr4.y);
    m.z = xlv.z + fmaf(eav, we4.z, xr4.z);
    m.w = xlv.w + fmaf(eav, we4.w, xr4.w);
    m.x = (m.x > 0.f) ? m.x : 0.2f * m.x;
    m.y = (m.y > 0.f) ? m.y : 0.2f * m.y;
    m.z = (m.z > 0.f) ? m.z : 0.2f * m.z;
    m.w = (m.w > 0.f) ? m.w : 0.2f * m.w;
    float p = fmaf(m.w, at4.w, fmaf(m.z, at4.z, fmaf(m.y, at4.y, m.x * at4.x)));
    #pragma unroll
    for (int off = 1; off < 16; off <<= 1) p += __shfl_xor(p, off);
    float nm = fmaxf(runmax, p);
    float sc = __expf(runmax - nm);   // first iter: exp(-inf)=0
    float wgt = __expf(p - nm);
    den = fmaf(den, sc, wgt);
    acc.x = fmaf(acc.x, sc, wgt * xlv.x);
    acc.y = fmaf(acc.y, sc, wgt * xlv.y);
    acc.z = fmaf(acc.z, sc, wgt * xlv.z);
    acc.w = fmaf(acc.w, sc, wgt * xlv.w);
    runmax = nm;
    xu = xu2; eav = ea2; j = jn;
  }

  float inv = (end > beg) ? (1.f / den) : 0.f;
  float4 b4 = *(const float4*)&bias[4 * lane];
  float4 o;
  o.x = fmaxf(fmaf(acc.x, inv, b4.x), 0.f);
  o.y = fmaxf(fmaf(acc.y, inv, b4.y), 0.f);
  o.z = fmaxf(fmaf(acc.z, inv, b4.z), 0.f);
  o.w = fmaxf(fmaf(acc.w, inv, b4.w), 0.f);
  *(float4*)&out[n * HCD + 4 * lane] = o;
}

// ---------------- global mean pool (batch is sorted) ----------------

__device__ __forceinline__ int lbound(const int* __restrict__ a, int n, int key) {
  int lo = 0, hi = n;
  while (lo < hi) { int mid = (lo + hi) >> 1; if (a[mid] < key) lo = mid + 1; else hi = mid; }
  return lo;
}

__global__ __launch_bounds__(256) void pool_kernel(const float* __restrict__ h,
                                                   const int* __restrict__ batch,
                                                   float* __restrict__ gmean) {
  int g = blockIdx.x;
  int t = threadIdx.x, lane = t & 63, wv = t >> 6;
  __shared__ int sb, se;
  if (t == 0) {
    sb = lbound(batch, N_NODES, g);
    se = lbound(batch, N_NODES, g + 1);
  }
  __syncthreads();
  int beg = sb, end = se;
  float4 acc = make_float4(0.f, 0.f, 0.f, 0.f);
  for (int n = beg + wv; n < end; n += 4) {
    float4 v = *(const float4*)&h[n * HCD + 4 * lane];
    acc.x += v.x; acc.y += v.y; acc.z += v.z; acc.w += v.w;
  }
  __shared__ float4 sacc[4][64];
  sacc[wv][lane] = acc;
  __syncthreads();
  if (wv == 0) {
    float4 a0 = sacc[0][lane], a1 = sacc[1][lane], a2 = sacc[2][lane], a3 = sacc[3][lane];
    float cnt = (float)((end - beg) > 1 ? (end - beg) : 1);
    float inv = 1.f / cnt;
    float4 o;
    o.x = (a0.x + a1.x + a2.x + a3.x) * inv;
    o.y = (a0.y + a1.y + a2.y + a3.y) * inv;
    o.z = (a0.z + a1.z + a2.z + a3.z) * inv;
    o.w = (a0.w + a1.w + a2.w + a3.w) * inv;
    *(float4*)&gmean[g * HCD + 4 * lane] = o;
  }
}

// ---------------- post MLP: Linear->LN->ReLU->Linear->ReLU->head ----------------

__global__ __launch_bounds__(128) void mlp_kernel(
    const float* __restrict__ gmean,
    const float* __restrict__ p1_w, const float* __restrict__ p1_b,
    const float* __restrict__ ln_g, const float* __restrict__ ln_b,
    const float* __restrict__ p2_w, const float* __restrict__ p2_b,
    const float* __restrict__ head_w, const float* __restrict__ head_b,
    float* __restrict__ out)
{
  int g = blockIdx.x, t = threadIdx.x;
  __shared__ float gv[256];
  __shared__ float zs[128];
  __shared__ float z2s[64];
  __shared__ float sums[2][2];
  gv[t] = gmean[g * 256 + t];
  gv[t + 128] = gmean[g * 256 + 128 + t];
  __syncthreads();
  float acc = p1_b[t];
  for (int k = 0; k < 256; ++k) acc += gv[k] * p1_w[k * 128 + t];
  float s1 = acc, s2 = acc * acc;
  #pragma unroll
  for (int off = 32; off >= 1; off >>= 1) {
    s1 += __shfl_xor(s1, off);
    s2 += __shfl_xor(s2, off);
  }
  int wid = t >> 6, lane = t & 63;
  if (lane == 0) { sums[wid][0] = s1; sums[wid][1] = s2; }
  __syncthreads();
  float S1 = sums[0][0] + sums[1][0];
  float S2 = sums[0][1] + sums[1][1];
  float mu = S1 * (1.f / 128.f);
  float var = S2 * (1.f / 128.f) - mu * mu;
  float rstd = rsqrtf(var + 1e-5f);
  float z = (acc - mu) * rstd * ln_g[t] + ln_b[t];
  zs[t] = fmaxf(z, 0.f);
  __syncthreads();
  if (t < 64) {
    float a2 = p2_b[t];
    for (int k = 0; k < 128; ++k) a2 += zs[k] * p2_w[k * 64 + t];
    z2s[t] = fmaxf(a2, 0.f);
  }
  __syncthreads();
  if (t < 64) {
    float p = z2s[t] * head_w[t];
    #pragma unroll
    for (int off = 32; off >= 1; off >>= 1) p += __shfl_xor(p, off);
    if (t == 0) out[g] = p + head_b[0];
  }
}

// ---------------- launch ----------------

extern "C" void kernel_launch(void* const* d_in, const int* in_sizes, int n_in,
                              void* d_out, int out_size, void* d_ws, size_t ws_size,
                              hipStream_t stream) {
  const float* x       = (const float*)d_in[0];
  const float* ea      = (const float*)d_in[1];
  const int*   eidx    = (const int*)d_in[2];
  const int*   batch   = (const int*)d_in[3];
  const float* enc_w   = (const float*)d_in[4];
  const float* enc_b   = (const float*)d_in[5];
  const float* g1_wl   = (const float*)d_in[6];
  const float* g1_bl   = (const float*)d_in[7];
  const float* g1_wr   = (const float*)d_in[8];
  const float* g1_br   = (const float*)d_in[9];
  const float* g1_we   = (const float*)d_in[10];
  const float* g1_att  = (const float*)d_in[11];
  const float* g1_bias = (const float*)d_in[12];
  const float* g2_wl   = (const float*)d_in[13];
  const float* g2_bl   = (const float*)d_in[14];
  const float* g2_wr   = (const float*)d_in[15];
  const float* g2_br   = (const float*)d_in[16];
  const float* g2_we   = (const float*)d_in[17];
  const float* g2_att  = (const float*)d_in[18];
  const float* g2_bias = (const float*)d_in[19];
  const float* p1_w    = (const float*)d_in[20];
  const float* p1_b    = (const float*)d_in[21];
  const float* ln_g    = (const float*)d_in[22];
  const float* ln_b    = (const float*)d_in[23];
  const float* p2_w    = (const float*)d_in[24];
  const float* p2_b    = (const float*)d_in[25];
  const float* head_w  = (const float*)d_in[26];
  const float* head_b  = (const float*)d_in[27];

  const int* src = eidx;
  const int* dst = eidx + N_EDGES;

  char* wsp = (char*)d_ws;
  size_t off = 0;
  auto alloc = [&](size_t bytes) -> void* {
    void* p = wsp + off;
    off += (bytes + 255) & ~(size_t)255;
    return p;
  };
  float*          h0     = (float*)alloc((size_t)N_NODES * 64 * 4);
  float*          hA     = (float*)alloc((size_t)N_NODES * 256 * 4);
  unsigned short* xlb    = (unsigned short*)alloc((size_t)N_NODES * 256 * 2);
  float*          xr     = (float*)alloc((size_t)N_NODES * 256 * 4);
  int*            counts = (int*)alloc((size_t)N_NODES * 4);
  int*            offs   = (int*)alloc((size_t)(N_NODES + 1) * 4);
  int*            cursor = (int*)alloc((size_t)N_NODES * 4);
  int*            bsum   = (int*)alloc((size_t)256 * 4);
  int*            ssrc   = (int*)alloc((size_t)N_EDGES * 4);
  float*          seaf   = (float*)alloc((size_t)N_EDGES * 4);
  float*          gmean  = (float*)alloc((size_t)N_GRAPHS * 256 * 4);

  const int NBLK = (N_NODES + 255) / 256;  // 196

  // --- CSR by dst (built once, reused by both GAT layers) ---
  zero_i32<<<NBLK, 256, 0, stream>>>(counts, N_NODES);
  hist_kernel<<<(N_EDGES + 255) / 256, 256, 0, stream>>>(dst, counts, N_EDGES);
  scan1_kernel<<<NBLK, 256, 0, stream>>>(counts, offs, bsum, N_NODES);
  scan2_kernel<<<1, 256, 0, stream>>>(bsum, NBLK);
  scan3_kernel<<<(N_NODES + 256) / 256, 256, 0, stream>>>(offs, bsum, cursor, N_NODES);
  scatter_kernel<<<(N_EDGES + 255) / 256, 256, 0, stream>>>(src, dst, ea, cursor, ssrc, seaf, N_EDGES);

  // --- encoder ---
  encoder_kernel<<<(N_NODES * 64 + 255) / 256, 256, 0, stream>>>(x, enc_w, enc_b, h0, N_NODES);

  const dim3 tgrid((N_NODES + 31) / 32, 2);
  const int AGG_BLOCKS = (N_NODES + 3) / 4;   // 12500, 1 wave per node

  // --- GAT layer 1 (in = 64) ---
  transform_kernel<64><<<tgrid, 256, 0, stream>>>(
      h0, g1_wl, g1_bl, g1_wr, g1_br, xlb, xr, N_NODES);
  gat_aggregate_kernel<<<AGG_BLOCKS, 256, 0, stream>>>(
      xlb, xr, offs, ssrc, seaf, g1_we, g1_att, g1_bias, hA, N_NODES);

  // --- GAT layer 2 (in = 256) ---
  transform_kernel<256><<<tgrid, 256, 0, stream>>>(
      hA, g2_wl, g2_bl, g2_wr, g2_br, xlb, xr, N_NODES);
  gat_aggregate_kernel<<<AGG_BLOCKS, 256, 0, stream>>>(
      xlb, xr, offs, ssrc, seaf, g2_we, g2_att, g2_bias, hA, N_NODES);

  // --- pool + MLP head ---
  pool_kernel<<<N_GRAPHS, 256, 0, stream>>>(hA, batch, gmean);
  mlp_kernel<<<N_GRAPHS, 128, 0, stream>>>(gmean, p1_w, p1_b, ln_g, ln_b,
                                           p2_w, p2_b, head_w, head_b, (float*)d_out);
}